// Round 1
// baseline (630.675 us; speedup 1.0000x reference)
//
#include <hip/hip_runtime.h>
#include <hip/hip_bf16.h>
#include <math.h>

#define N 8192
#define HD 64
#define NEGV -1000000000.0f
#define EPSV 1e-05f
#define NSPLIT 4
#define CPS (N / NSPLIT)   // columns per split = 2048
#define NTILE (CPS / 64)   // 32 tiles of 64 cols

// workspace layout in floats (all offsets multiples of 64 -> 256B aligned)
#define WS_SCAL 0
#define WS_H    64
#define WS_Q    (WS_H + N * HD)
#define WS_KT   (WS_Q + N * HD)
#define WS_M    (WS_KT + N * HD)
#define WS_ST   (WS_M + N * HD)
#define WS_SBI  (WS_ST + N)
#define WS_DEN  (WS_SBI + N)
#define WS_AGG  (WS_DEN + NSPLIT * N)

static __device__ __forceinline__ float bf2f(unsigned short u) {
    return __uint_as_float(((unsigned)u) << 16);
}

// ---------------- Kernel A: scalar prep ----------------
// gate_factor = mean(sigmoid(tc @ wg + bg)); fold 0.125*gate into q-scale.
// coef = stateful_bias[0] * (1 - tc[0]).
__global__ void prep_k(const float* __restrict__ tc, const float* __restrict__ wg,
                       const float* __restrict__ bg, const float* __restrict__ sbias,
                       float* __restrict__ scal) {
    int j = threadIdx.x;  // 64 threads
    float v = tc[0] * wg[j] + tc[1] * wg[64 + j] + bg[j];
    float g = 1.0f / (1.0f + __expf(-v));
    for (int off = 32; off; off >>= 1) g += __shfl_xor(g, off, 64);
    if (j == 0) {
        scal[0] = 0.125f * (g * (1.0f / 64.0f));   // qscale
        scal[1] = sbias[0] * (1.0f - tc[0]);        // coef
    }
}

// ---------------- Kernel B: per-row embed (h, q*, kT, m, st, sbi) ----------------
__global__ __launch_bounds__(256) void embed_k(
    const float* __restrict__ nf, const float* __restrict__ tc,
    const float* __restrict__ w1, const float* __restrict__ b1,
    const float* __restrict__ w2, const float* __restrict__ b2,
    const float* __restrict__ wq, const float* __restrict__ bq,
    const float* __restrict__ wk, const float* __restrict__ bk,
    const float* __restrict__ wm, const float* __restrict__ bm,
    float* __restrict__ ws)
{
    const int w = threadIdx.x >> 6, lane = threadIdx.x & 63;
    const int row = blockIdx.x * 4 + w;
    __shared__ float ts[4][64], hs[4][64];
    const float qscale = ws[WS_SCAL + 0];
    const float coef   = ws[WS_SCAL + 1];
    const float f0 = nf[row * 3], f1 = nf[row * 3 + 1], f2 = nf[row * 3 + 2];
    const float t0 = tc[0], t1 = tc[1];
    float v = b1[lane];
    v = fmaf(f0, w1[lane], v);
    v = fmaf(f1, w1[64 + lane], v);
    v = fmaf(f2, w1[128 + lane], v);
    v = fmaf(t0, w1[192 + lane], v);
    v = fmaf(t1, w1[256 + lane], v);
    ts[w][lane] = fmaxf(v, 0.0f);
    __syncthreads();
    float hv = b2[lane];
    #pragma unroll 8
    for (int j = 0; j < 64; j++) hv = fmaf(ts[w][j], w2[j * 64 + lane], hv);
    hs[w][lane] = hv;
    ws[WS_H + row * 64 + lane] = hv;
    __syncthreads();
    float qv = bq[lane], kv = bk[lane], mv = bm[lane];
    #pragma unroll 4
    for (int j = 0; j < 64; j++) {
        const float hj = hs[w][j];
        qv = fmaf(hj, wq[j * 64 + lane], qv);
        kv = fmaf(hj, wk[j * 64 + lane], kv);
        mv = fmaf(hj, wm[j * 64 + lane], mv);
    }
    ws[WS_Q + row * 64 + lane] = qv * qscale;
    ws[WS_KT + lane * N + row] = kv;                 // k transposed: kT[c][row]
    ws[WS_M + row * 64 + lane] = mv;
    if (lane == 0) {
        ws[WS_ST + row]  = f2;
        ws[WS_SBI + row] = f2 * coef;
    }
}

// ---------------- Kernel C: streaming attention (the big one) ----------------
// Block: 256 threads, tile 64 rows x 64 cols, 4x4 register blocking per thread.
// Grid: (N/64 row-blocks, NSPLIT column splits). Partial denom/agg to ws.
__global__ __launch_bounds__(256, 2) void attn_k(const float* __restrict__ adj,
                                                 float* __restrict__ ws)
{
    const int rb = blockIdx.x, sp = blockIdx.y;
    const int i0 = rb * 64, j0 = sp * CPS;
    const int tid = threadIdx.x;
    const int tx = tid & 15, ty = tid >> 4;   // 16x16 thread grid

    __shared__ float qT[64][68];              // qT[c][row]  17.4 KB
    __shared__ float kTs[64][68];             // kTs[c][jj]  17.4 KB
    __shared__ float ms[64][68];              // ms[jj][ch]  17.4 KB
    __shared__ __hip_bfloat16 pT[64][68];     // pT[jj][row]  8.7 KB
    __shared__ float sbis[64], sts[64];

    const float* q  = ws + WS_Q;
    const float* kT = ws + WS_KT;
    const float* m  = ws + WS_M;

    // stage q tile (transposed) once per block
    for (int it = 0; it < 16; it++) {
        const int e = it * 256 + tid;
        const int r = e >> 6, c = e & 63;
        qT[c][r] = q[(size_t)(i0 + r) * 64 + c];
    }
    if (tid < 64) sbis[tid] = ws[WS_SBI + i0 + tid];

    float agg[4][4] = {};
    float den[4] = {};

    for (int t = 0; t < NTILE; t++) {
        const int j = j0 + t * 64;
        __syncthreads();  // previous tile's PV done before restaging
        for (int it = 0; it < 16; it++) {
            const int e = it * 256 + tid;
            const int a = e >> 6, b = e & 63;
            kTs[a][b] = kT[(size_t)a * N + j + b];       // coalesced, conflict-free
            ms[a][b]  = m[(size_t)(j + a) * 64 + b];     // coalesced, conflict-free
        }
        if (tid < 64) sts[tid] = ws[WS_ST + j + tid];
        __syncthreads();

        // init scores with topo + sb, then accumulate scaled q.k
        float s[4][4];
        #pragma unroll
        for (int v = 0; v < 4; v++) {
            const int r = ty * 4 + v;
            const float4 a4 = *(const float4*)&adj[(size_t)(i0 + r) * N + j + tx * 4];
            const float aa[4] = {a4.x, a4.y, a4.z, a4.w};
            const float sbv = sbis[r];
            #pragma unroll
            for (int u = 0; u < 4; u++)
                s[v][u] = (aa[u] == 0.0f ? NEGV : aa[u]) + sbv * sts[tx * 4 + u];
        }
        #pragma unroll 4
        for (int cc = 0; cc < 64; cc++) {
            const float4 qv = *(const float4*)&qT[cc][ty * 4];
            const float4 kv = *(const float4*)&kTs[cc][tx * 4];
            const float qa[4] = {qv.x, qv.y, qv.z, qv.w};
            const float ka[4] = {kv.x, kv.y, kv.z, kv.w};
            #pragma unroll
            for (int v = 0; v < 4; v++)
                #pragma unroll
                for (int u = 0; u < 4; u++)
                    s[v][u] = fmaf(qa[v], ka[u], s[v][u]);
        }
        // exp, denom partials, write P (bf16) transposed for the PV phase
        #pragma unroll
        for (int v = 0; v < 4; v++) {
            #pragma unroll
            for (int u = 0; u < 4; u++) {
                const float p = __expf(s[v][u]);
                den[v] += p;
                pT[tx * 4 + u][ty * 4 + v] = __float2bfloat16(p);
            }
        }
        __syncthreads();
        // PV: agg[row][ch] += p[row][jj] * m[jj][ch]
        #pragma unroll 4
        for (int jj = 0; jj < 64; jj++) {
            const ushort4 pu = *(const ushort4*)&pT[jj][ty * 4];
            const float4 mv = *(const float4*)&ms[jj][tx * 4];
            const float pa[4] = {bf2f(pu.x), bf2f(pu.y), bf2f(pu.z), bf2f(pu.w)};
            const float ma[4] = {mv.x, mv.y, mv.z, mv.w};
            #pragma unroll
            for (int v = 0; v < 4; v++)
                #pragma unroll
                for (int u = 0; u < 4; u++)
                    agg[v][u] = fmaf(pa[v], ma[u], agg[v][u]);
        }
    }

    // write agg partials (rows ty*4+v, channels tx*4..tx*4+3)
    float* aggp = ws + WS_AGG + (size_t)sp * N * 64;
    #pragma unroll
    for (int v = 0; v < 4; v++) {
        const int r = i0 + ty * 4 + v;
        float4 o = make_float4(agg[v][0], agg[v][1], agg[v][2], agg[v][3]);
        *(float4*)&aggp[(size_t)r * 64 + tx * 4] = o;
    }
    // reduce denom across the 16 tx-threads of each row (they are consecutive lanes)
    #pragma unroll
    for (int v = 0; v < 4; v++) {
        float d = den[v];
        for (int off = 8; off; off >>= 1) d += __shfl_xor(d, off, 16);
        if (tx == 0) ws[WS_DEN + sp * N + i0 + ty * 4 + v] = d;
    }
}

// ---------------- Kernel D: combine splits + LayerNorm + final MLP ----------------
__global__ __launch_bounds__(256) void final_k(
    const float* __restrict__ sa, const float* __restrict__ ln_g,
    const float* __restrict__ ln_b,
    const float* __restrict__ wa1, const float* __restrict__ ba1,
    const float* __restrict__ wa2, const float* __restrict__ ba2,
    const float* __restrict__ ws, float* __restrict__ out)
{
    const int w = threadIdx.x >> 6, lane = threadIdx.x & 63;
    const int row = blockIdx.x * 4 + w;
    __shared__ float es[4][64], hs2[4][64];
    float a = 0.0f;
    #pragma unroll
    for (int sp = 0; sp < NSPLIT; sp++)
        a += ws[WS_AGG + (size_t)sp * N * 64 + (size_t)row * 64 + lane];
    float d = 0.0f;
    #pragma unroll
    for (int sp = 0; sp < NSPLIT; sp++) d += ws[WS_DEN + sp * N + row];
    const float z = ws[WS_H + row * 64 + lane] + a / d;
    float mu = z;
    for (int off = 32; off; off >>= 1) mu += __shfl_xor(mu, off, 64);
    mu *= (1.0f / 64.0f);
    const float zc = z - mu;
    float var = zc * zc;
    for (int off = 32; off; off >>= 1) var += __shfl_xor(var, off, 64);
    var *= (1.0f / 64.0f);
    const float emb = zc * rsqrtf(var + EPSV) * ln_g[lane] + ln_b[lane];
    es[w][lane] = emb;
    __syncthreads();
    const float sa0 = sa[row * 2], sa1 = sa[row * 2 + 1];
    float hv = ba1[lane];
    #pragma unroll 8
    for (int c = 0; c < 64; c++) hv = fmaf(es[w][c], wa1[c * 64 + lane], hv);
    hv = fmaf(sa0, wa1[64 * 64 + lane], hv);
    hv = fmaf(sa1, wa1[65 * 64 + lane], hv);
    hs2[w][lane] = fmaxf(hv, 0.0f);
    __syncthreads();
    if (lane < 3) {
        float o = ba2[lane];
        for (int u = 0; u < 64; u++) o = fmaf(hs2[w][u], wa2[u * 3 + lane], o);
        out[row * 3 + lane] = o;
    }
}

extern "C" void kernel_launch(void* const* d_in, const int* in_sizes, int n_in,
                              void* d_out, int out_size, void* d_ws, size_t ws_size,
                              hipStream_t stream)
{
    const float* nf  = (const float*)d_in[0];
    const float* adj = (const float*)d_in[1];
    const float* tc  = (const float*)d_in[2];
    const float* sa  = (const float*)d_in[3];
    const float* w1  = (const float*)d_in[4];
    const float* b1  = (const float*)d_in[5];
    const float* w2  = (const float*)d_in[6];
    const float* b2  = (const float*)d_in[7];
    const float* wq  = (const float*)d_in[8];
    const float* bq  = (const float*)d_in[9];
    const float* wk  = (const float*)d_in[10];
    const float* bk  = (const float*)d_in[11];
    const float* wg  = (const float*)d_in[12];
    const float* bg  = (const float*)d_in[13];
    const float* sb  = (const float*)d_in[14];
    const float* wm  = (const float*)d_in[15];
    const float* bm  = (const float*)d_in[16];
    const float* lng = (const float*)d_in[17];
    const float* lnb = (const float*)d_in[18];
    const float* wa1 = (const float*)d_in[19];
    const float* ba1 = (const float*)d_in[20];
    const float* wa2 = (const float*)d_in[21];
    const float* ba2 = (const float*)d_in[22];
    float* ws  = (float*)d_ws;
    float* out = (float*)d_out;

    prep_k<<<1, 64, 0, stream>>>(tc, wg, bg, sb, ws + WS_SCAL);
    embed_k<<<N / 4, 256, 0, stream>>>(nf, tc, w1, b1, w2, b2, wq, bq, wk, bk,
                                       wm, bm, ws);
    attn_k<<<dim3(N / 64, NSPLIT), 256, 0, stream>>>(adj, ws);
    final_k<<<N / 4, 256, 0, stream>>>(sa, lng, lnb, wa1, ba1, wa2, ba2, ws, out);
}

// Round 3
// 474.237 us; speedup vs baseline: 1.3299x; 1.3299x over previous
//
#include <hip/hip_runtime.h>
#include <hip/hip_bf16.h>
#include <math.h>

#define N 8192
#define NEGV -1000000000.0f
#define EPSV 1e-05f
#define NSPLIT 4
#define CPS (N / NSPLIT)   // 2048 columns per split
#define NTILE (CPS / 64)   // 32 tiles

typedef short bf16x8 __attribute__((ext_vector_type(8)));
typedef float f32x4 __attribute__((ext_vector_type(4)));
typedef unsigned short u16;

// ---- float workspace layout ----
#define WS_SCAL 0
#define WS_H    64                        // N*64 fp32
#define WS_ST   (WS_H + N * 64)           // N
#define WS_SBI  (WS_ST + N)               // N
#define WS_DEN  (WS_SBI + N)              // NSPLIT*N
#define WS_AGG  (WS_DEN + NSPLIT * N)     // NSPLIT*N*64
#define WS_F_END (WS_AGG + NSPLIT * N * 64)
// ---- u16 (bf16) region, offsets in u16 units from (u16*)ws ----
#define WU_BASE (WS_F_END * 2)
#define WU_QB (WU_BASE)                   // N*64
#define WU_KB (WU_BASE + N * 64)          // N*64
#define WU_MB (WU_BASE + 2 * N * 64)      // N*64 (row-major, transposed later)
#define WU_MT (WU_BASE + 3 * N * 64)      // 64*N

static __device__ __forceinline__ u16 f2bf(float f) {
    __hip_bfloat16 h = __float2bfloat16(f);
    return *(u16*)&h;
}

// ---------------- Kernel A: scalar prep ----------------
__global__ void prep_k(const float* __restrict__ tc, const float* __restrict__ wg,
                       const float* __restrict__ bg, const float* __restrict__ sbias,
                       float* __restrict__ scal) {
    int j = threadIdx.x;  // 64 threads
    float v = tc[0] * wg[j] + tc[1] * wg[64 + j] + bg[j];
    float g = 1.0f / (1.0f + __expf(-v));
    for (int off = 32; off; off >>= 1) g += __shfl_xor(g, off, 64);
    if (j == 0) {
        scal[0] = 0.125f * (g * (1.0f / 64.0f));   // qscale (gate mean + 1/sqrt(64) folded)
        scal[1] = sbias[0] * (1.0f - tc[0]);        // coef
    }
}

// ---------------- Kernel B: embed (h fp32; q,k,m bf16; st, sbi) ----------------
__global__ __launch_bounds__(256) void embed_k(
    const float* __restrict__ nf, const float* __restrict__ tc,
    const float* __restrict__ w1, const float* __restrict__ b1,
    const float* __restrict__ w2, const float* __restrict__ b2,
    const float* __restrict__ wq, const float* __restrict__ bq,
    const float* __restrict__ wk, const float* __restrict__ bk,
    const float* __restrict__ wm, const float* __restrict__ bm,
    float* __restrict__ ws)
{
    const int w = threadIdx.x >> 6, lane = threadIdx.x & 63;
    const int row = blockIdx.x * 4 + w;
    __shared__ float ts[4][64], hs[4][64];
    const float qscale = ws[WS_SCAL + 0];
    const float coef   = ws[WS_SCAL + 1];
    const float f0 = nf[row * 3], f1 = nf[row * 3 + 1], f2 = nf[row * 3 + 2];
    const float t0 = tc[0], t1 = tc[1];
    float v = b1[lane];
    v = fmaf(f0, w1[lane], v);
    v = fmaf(f1, w1[64 + lane], v);
    v = fmaf(f2, w1[128 + lane], v);
    v = fmaf(t0, w1[192 + lane], v);
    v = fmaf(t1, w1[256 + lane], v);
    ts[w][lane] = fmaxf(v, 0.0f);
    __syncthreads();
    float hv = b2[lane];
    #pragma unroll 8
    for (int j = 0; j < 64; j++) hv = fmaf(ts[w][j], w2[j * 64 + lane], hv);
    hs[w][lane] = hv;
    ws[WS_H + row * 64 + lane] = hv;
    __syncthreads();
    float qv = bq[lane], kv = bk[lane], mv = bm[lane];
    #pragma unroll 4
    for (int j = 0; j < 64; j++) {
        const float hj = hs[w][j];
        qv = fmaf(hj, wq[j * 64 + lane], qv);
        kv = fmaf(hj, wk[j * 64 + lane], kv);
        mv = fmaf(hj, wm[j * 64 + lane], mv);
    }
    u16* wu = (u16*)ws;
    wu[WU_QB + row * 64 + lane] = f2bf(qv * qscale);
    wu[WU_KB + row * 64 + lane] = f2bf(kv);
    wu[WU_MB + row * 64 + lane] = f2bf(mv);
    if (lane == 0) {
        ws[WS_ST + row]  = f2;
        ws[WS_SBI + row] = f2 * coef;
    }
}

// ---------------- Kernel B2: transpose M (bf16) ----------------
// NOTE: uint4 = 16 BYTES = 8 u16 elements. Each thread moves 16 u16 (two uint4).
__global__ __launch_bounds__(256) void transp_k(float* __restrict__ ws) {
    const u16* mb = (const u16*)ws + WU_MB;
    u16* mt = (u16*)ws + WU_MT;
    __shared__ __align__(16) u16 tile[64][72];
    const int i0 = blockIdx.x * 64;
    const int t = threadIdx.x;
    {
        const int r = t >> 2, cb = (t & 3) * 16;   // 4 threads/row x 16 u16 = 64 cols
        *(uint4*)&tile[r][cb]     = *(const uint4*)&mb[(size_t)(i0 + r) * 64 + cb];
        *(uint4*)&tile[r][cb + 8] = *(const uint4*)&mb[(size_t)(i0 + r) * 64 + cb + 8];
    }
    __syncthreads();
    const int c = t >> 2, rb = (t & 3) * 16;
    u16 tmp[16];
    #pragma unroll
    for (int i = 0; i < 16; i++) tmp[i] = tile[rb + i][c];
    *(uint4*)&mt[(size_t)c * N + i0 + rb]     = *(uint4*)&tmp[0];
    *(uint4*)&mt[(size_t)c * N + i0 + rb + 8] = *(uint4*)&tmp[8];
}

// ---------------- Kernel C: MFMA streaming attention ----------------
// Block: 256 threads (4 waves), 64 rows x 64 cols per tile, double-buffered K/Mt.
__global__ __launch_bounds__(256, 2) void attn_k(const float* __restrict__ adj,
                                                 float* __restrict__ ws)
{
    const int rb = blockIdx.x, sp = blockIdx.y;
    const int i0 = rb * 64, j0 = sp * CPS;
    const int tid = threadIdx.x;
    const int w = tid >> 6, lane = tid & 63;
    const int quad = lane >> 4, n16 = lane & 15;
    const int m0 = w * 16;

    __shared__ __align__(16) u16 qs[64][72];        //  9.2 KB
    __shared__ __align__(16) u16 ks[2][64][72];     // 18.4 KB
    __shared__ __align__(16) u16 ms[2][64][72];     // 18.4 KB
    __shared__ __align__(16) u16 ps[64][72];        //  9.2 KB
    __shared__ float sts[2][64];
    __shared__ float sbis[64];

    const u16* qb = (const u16*)ws + WU_QB;
    const u16* kb = (const u16*)ws + WU_KB;
    const u16* mt = (const u16*)ws + WU_MT;

    // staging map: 4 threads per row, each thread moves 16 u16 (two uint4 = 32 B)
    const int sr = tid >> 2, scb = (tid & 3) * 16;

    // stage Q tile + sbi + tile 0 of K/Mt
    *(uint4*)&qs[sr][scb]     = *(const uint4*)&qb[(size_t)(i0 + sr) * 64 + scb];
    *(uint4*)&qs[sr][scb + 8] = *(const uint4*)&qb[(size_t)(i0 + sr) * 64 + scb + 8];
    if (tid < 64) sbis[tid] = ws[WS_SBI + i0 + tid];
    {
        const int jt = j0;
        *(uint4*)&ks[0][sr][scb]     = *(const uint4*)&kb[(size_t)(jt + sr) * 64 + scb];
        *(uint4*)&ks[0][sr][scb + 8] = *(const uint4*)&kb[(size_t)(jt + sr) * 64 + scb + 8];
        *(uint4*)&ms[0][sr][scb]     = *(const uint4*)&mt[(size_t)sr * N + jt + scb];
        *(uint4*)&ms[0][sr][scb + 8] = *(const uint4*)&mt[(size_t)sr * N + jt + scb + 8];
        if (tid < 64) sts[0][tid] = ws[WS_ST + jt + tid];
    }
    __syncthreads();

    // Q fragments (fixed for the whole block)
    const bf16x8 aq0 = *(const bf16x8*)&qs[m0 + n16][quad * 8];
    const bf16x8 aq1 = *(const bf16x8*)&qs[m0 + n16][32 + quad * 8];

    f32x4 acc[4];
    #pragma unroll
    for (int i = 0; i < 4; i++) acc[i] = (f32x4){0.f, 0.f, 0.f, 0.f};
    float den[4] = {0.f, 0.f, 0.f, 0.f};
    float sbr[4];
    #pragma unroll
    for (int v = 0; v < 4; v++) sbr[v] = sbis[m0 + quad * 4 + v];

    for (int t = 0; t < NTILE; t++) {
        const int cur = t & 1;
        const int jt = j0 + t * 64;

        // adj loads for this tile (16 dwords, issued early)
        float aa[4][4];
        #pragma unroll
        for (int reg = 0; reg < 4; reg++) {
            const size_t rowb = (size_t)(i0 + m0 + quad * 4 + reg) * N + jt + n16;
            #pragma unroll
            for (int ct = 0; ct < 4; ct++) aa[ct][reg] = adj[rowb + ct * 16];
        }

        // stage next tile into the other buffer (overlaps S-phase)
        if (t + 1 < NTILE) {
            const int jn = jt + 64;
            *(uint4*)&ks[cur ^ 1][sr][scb]     = *(const uint4*)&kb[(size_t)(jn + sr) * 64 + scb];
            *(uint4*)&ks[cur ^ 1][sr][scb + 8] = *(const uint4*)&kb[(size_t)(jn + sr) * 64 + scb + 8];
            *(uint4*)&ms[cur ^ 1][sr][scb]     = *(const uint4*)&mt[(size_t)sr * N + jn + scb];
            *(uint4*)&ms[cur ^ 1][sr][scb + 8] = *(const uint4*)&mt[(size_t)sr * N + jn + scb + 8];
            if (tid < 64) sts[cur ^ 1][tid] = ws[WS_ST + jn + tid];
        }

        // S = Q K^T (per-wave 16x64 strip), epilogue, write P to LDS
        #pragma unroll
        for (int ct = 0; ct < 4; ct++) {
            const bf16x8 b0 = *(const bf16x8*)&ks[cur][ct * 16 + n16][quad * 8];
            const bf16x8 b1 = *(const bf16x8*)&ks[cur][ct * 16 + n16][32 + quad * 8];
            f32x4 s = {0.f, 0.f, 0.f, 0.f};
            s = __builtin_amdgcn_mfma_f32_16x16x32_bf16(aq0, b0, s, 0, 0, 0);
            s = __builtin_amdgcn_mfma_f32_16x16x32_bf16(aq1, b1, s, 0, 0, 0);
            const float stc = sts[cur][ct * 16 + n16];
            #pragma unroll
            for (int reg = 0; reg < 4; reg++) {
                const float a = aa[ct][reg];
                const float sc = s[reg] + (a == 0.0f ? NEGV : a) + sbr[reg] * stc;
                const float p = __expf(sc);
                den[reg] += p;
                ps[m0 + quad * 4 + reg][ct * 16 + n16] = f2bf(p);
            }
        }
        __syncthreads();

        // PV: acc += P (16x64 strip) @ M (64x64)
        const bf16x8 ap0 = *(const bf16x8*)&ps[m0 + n16][quad * 8];
        const bf16x8 ap1 = *(const bf16x8*)&ps[m0 + n16][32 + quad * 8];
        #pragma unroll
        for (int nt = 0; nt < 4; nt++) {
            const bf16x8 b0 = *(const bf16x8*)&ms[cur][nt * 16 + n16][quad * 8];
            const bf16x8 b1 = *(const bf16x8*)&ms[cur][nt * 16 + n16][32 + quad * 8];
            acc[nt] = __builtin_amdgcn_mfma_f32_16x16x32_bf16(ap0, b0, acc[nt], 0, 0, 0);
            acc[nt] = __builtin_amdgcn_mfma_f32_16x16x32_bf16(ap1, b1, acc[nt], 0, 0, 0);
        }
        __syncthreads();
    }

    // write agg partials (C-layout rows) + reduced denominators
    float* aggp = ws + WS_AGG + (size_t)sp * N * 64;
    #pragma unroll
    for (int nt = 0; nt < 4; nt++) {
        #pragma unroll
        for (int reg = 0; reg < 4; reg++) {
            aggp[(size_t)(i0 + m0 + quad * 4 + reg) * 64 + nt * 16 + n16] = acc[nt][reg];
        }
    }
    #pragma unroll
    for (int reg = 0; reg < 4; reg++) {
        float d = den[reg];
        d += __shfl_xor(d, 1, 64);
        d += __shfl_xor(d, 2, 64);
        d += __shfl_xor(d, 4, 64);
        d += __shfl_xor(d, 8, 64);
        if (n16 == 0) ws[WS_DEN + sp * N + i0 + m0 + quad * 4 + reg] = d;
    }
}

// ---------------- Kernel D: combine + LayerNorm + final MLP ----------------
__global__ __launch_bounds__(256) void final_k(
    const float* __restrict__ sa, const float* __restrict__ ln_g,
    const float* __restrict__ ln_b,
    const float* __restrict__ wa1, const float* __restrict__ ba1,
    const float* __restrict__ wa2, const float* __restrict__ ba2,
    const float* __restrict__ ws, float* __restrict__ out)
{
    const int w = threadIdx.x >> 6, lane = threadIdx.x & 63;
    const int row = blockIdx.x * 4 + w;
    __shared__ float es[4][64], hs2[4][64];
    float a = 0.0f;
    #pragma unroll
    for (int sp = 0; sp < NSPLIT; sp++)
        a += ws[WS_AGG + (size_t)sp * N * 64 + (size_t)row * 64 + lane];
    float d = 0.0f;
    #pragma unroll
    for (int sp = 0; sp < NSPLIT; sp++) d += ws[WS_DEN + sp * N + row];
    const float z = ws[WS_H + row * 64 + lane] + a / d;
    float mu = z;
    for (int off = 32; off; off >>= 1) mu += __shfl_xor(mu, off, 64);
    mu *= (1.0f / 64.0f);
    const float zc = z - mu;
    float var = zc * zc;
    for (int off = 32; off; off >>= 1) var += __shfl_xor(var, off, 64);
    var *= (1.0f / 64.0f);
    const float emb = zc * rsqrtf(var + EPSV) * ln_g[lane] + ln_b[lane];
    es[w][lane] = emb;
    __syncthreads();
    const float sa0 = sa[row * 2], sa1 = sa[row * 2 + 1];
    float hv = ba1[lane];
    #pragma unroll 8
    for (int c = 0; c < 64; c++) hv = fmaf(es[w][c], wa1[c * 64 + lane], hv);
    hv = fmaf(sa0, wa1[64 * 64 + lane], hv);
    hv = fmaf(sa1, wa1[65 * 64 + lane], hv);
    hs2[w][lane] = fmaxf(hv, 0.0f);
    __syncthreads();
    if (lane < 3) {
        float o = ba2[lane];
        for (int u = 0; u < 64; u++) o = fmaf(hs2[w][u], wa2[u * 3 + lane], o);
        out[row * 3 + lane] = o;
    }
}

extern "C" void kernel_launch(void* const* d_in, const int* in_sizes, int n_in,
                              void* d_out, int out_size, void* d_ws, size_t ws_size,
                              hipStream_t stream)
{
    const float* nf  = (const float*)d_in[0];
    const float* adj = (const float*)d_in[1];
    const float* tc  = (const float*)d_in[2];
    const float* sa  = (const float*)d_in[3];
    const float* w1  = (const float*)d_in[4];
    const float* b1  = (const float*)d_in[5];
    const float* w2  = (const float*)d_in[6];
    const float* b2  = (const float*)d_in[7];
    const float* wq  = (const float*)d_in[8];
    const float* bq  = (const float*)d_in[9];
    const float* wk  = (const float*)d_in[10];
    const float* bk  = (const float*)d_in[11];
    const float* wg  = (const float*)d_in[12];
    const float* bg  = (const float*)d_in[13];
    const float* sb  = (const float*)d_in[14];
    const float* wm  = (const float*)d_in[15];
    const float* bm  = (const float*)d_in[16];
    const float* lng = (const float*)d_in[17];
    const float* lnb = (const float*)d_in[18];
    const float* wa1 = (const float*)d_in[19];
    const float* ba1 = (const float*)d_in[20];
    const float* wa2 = (const float*)d_in[21];
    const float* ba2 = (const float*)d_in[22];
    float* ws  = (float*)d_ws;
    float* out = (float*)d_out;

    prep_k<<<1, 64, 0, stream>>>(tc, wg, bg, sb, ws + WS_SCAL);
    embed_k<<<N / 4, 256, 0, stream>>>(nf, tc, w1, b1, w2, b2, wq, bq, wk, bk,
                                       wm, bm, ws);
    transp_k<<<N / 64, 256, 0, stream>>>(ws);
    attn_k<<<dim3(N / 64, NSPLIT), 256, 0, stream>>>(adj, ws);
    final_k<<<N / 4, 256, 0, stream>>>(sa, lng, lnb, wa1, ba1, wa2, ba2, ws, out);
}